// Round 1
// baseline (427.390 us; speedup 1.0000x reference)
//
#include <hip/hip_runtime.h>
#include <hip/hip_bf16.h>
#include <stdint.h>

typedef short bf16x8 __attribute__((ext_vector_type(8)));
typedef float f32x4 __attribute__((ext_vector_type(4)));

#define DEVI static __device__ __forceinline__

DEVI ushort f2bf(float f) {
  union { float f; uint32_t u; } v; v.f = f;
  uint32_t u = v.u;
  return (ushort)((u + 0x7fffu + ((u >> 16) & 1u)) >> 16);
}

DEVI void gload16(const void* g, void* l) {
  __builtin_amdgcn_global_load_lds((const __attribute__((address_space(1))) void*)g,
                                   (__attribute__((address_space(3))) void*)l,
                                   16, 0, 0);
}

// out[o][i] (or transposed) = (W[o][i] + sum_r up[o][r]*down[r][i]) * scale, as bf16
__global__ void fold_kernel(const float* __restrict__ W, const float* __restrict__ up,
                            const float* __restrict__ down, ushort* __restrict__ out,
                            int OUT, int IN, int transpose, float scale) {
  int idx = blockIdx.x * 256 + threadIdx.x;
  if (idx >= OUT * IN) return;
  int o = idx / IN, i = idx % IN;
  float v = W[idx];
#pragma unroll
  for (int r = 0; r < 4; ++r) v += up[o * 4 + r] * down[r * IN + i];
  v *= scale;
  out[transpose ? ((long)i * OUT + o) : idx] = f2bf(v);
}

__global__ void cvt_kernel(const float* __restrict__ in, ushort* __restrict__ out, int n8) {
  int idx = blockIdx.x * 256 + threadIdx.x;
  if (idx >= n8) return;
  const float4* p = (const float4*)(in + (long)idx * 8);
  float4 a = p[0], b = p[1];
  union { ushort us[8]; uint4 v; } r;
  r.us[0] = f2bf(a.x); r.us[1] = f2bf(a.y); r.us[2] = f2bf(a.z); r.us[3] = f2bf(a.w);
  r.us[4] = f2bf(b.x); r.us[5] = f2bf(b.y); r.us[6] = f2bf(b.z); r.us[7] = f2bf(b.w);
  *(uint4*)(out + (long)idx * 8) = r.v;
}

// Generic batched GEMM: C[m][n] = sum_k A[m][k] * B[n][k]  (B stored [N][K] row-major)
// batch z decomposed as (z>>3, z&7) with independent strides for A/B/C.
// A rows clamped to validM-1, B rows clamped to validN-1; C writes guarded.
__global__ __launch_bounds__(256) void gemm_bt(
    const ushort* __restrict__ A, long sA0, long sA1, int lda, int validM,
    const ushort* __restrict__ B, long sB0, long sB1, int ldb, int validN,
    float* __restrict__ C32, ushort* __restrict__ C16, long sC0, long sC1, int ldc,
    const float* __restrict__ bias, int K)
{
  __shared__ ushort As[128 * 32];
  __shared__ ushort Bs[128 * 32];

  const int z = blockIdx.z;
  const ushort* Ab = A + (long)(z >> 3) * sA0 + (long)(z & 7) * sA1;
  const ushort* Bb = B + (long)(z >> 3) * sB0 + (long)(z & 7) * sB1;
  const int m0 = blockIdx.x * 128;
  const int n0 = blockIdx.y * 128;
  const int tid = threadIdx.x;
  const int lane = tid & 63;
  const int wid = tid >> 6;

  // staging: chunk c in [0,512): row = c>>2, 8-elem segment = c&3. Two calls/thread/operand.
  const int c0 = tid;
  const int arow0 = min(m0 + (c0 >> 2), validM - 1);
  const int arow1 = min(m0 + (c0 >> 2) + 64, validM - 1);
  const int brow0 = min(n0 + (c0 >> 2), validN - 1);
  const int brow1 = min(n0 + (c0 >> 2) + 64, validN - 1);
  const int seg = (c0 & 3) * 8;

  const int wr = (wid >> 1) * 64;
  const int wc = (wid & 1) * 64;
  const int frow = lane & 15;
  const int fk = (lane >> 4) * 8;

  f32x4 acc[4][4] = {};

  for (int kt = 0; kt < K; kt += 32) {
    gload16(Ab + (long)arow0 * lda + kt + seg, As + c0 * 8);
    gload16(Ab + (long)arow1 * lda + kt + seg, As + (c0 + 256) * 8);
    gload16(Bb + (long)brow0 * ldb + kt + seg, Bs + c0 * 8);
    gload16(Bb + (long)brow1 * ldb + kt + seg, Bs + (c0 + 256) * 8);
    __syncthreads();

    bf16x8 af[4], bfr[4];
#pragma unroll
    for (int m = 0; m < 4; ++m)
      af[m] = *(const bf16x8*)(As + (wr + m * 16 + frow) * 32 + fk);
#pragma unroll
    for (int n = 0; n < 4; ++n)
      bfr[n] = *(const bf16x8*)(Bs + (wc + n * 16 + frow) * 32 + fk);
#pragma unroll
    for (int m = 0; m < 4; ++m)
#pragma unroll
      for (int n = 0; n < 4; ++n)
        acc[m][n] = __builtin_amdgcn_mfma_f32_16x16x32_bf16(af[m], bfr[n], acc[m][n], 0, 0, 0);
    __syncthreads();
  }

  const long cb = (long)(z >> 3) * sC0 + (long)(z & 7) * sC1;
  const int crow = m0 + wr + (lane >> 4) * 4;
  const int ccol = n0 + wc + (lane & 15);
#pragma unroll
  for (int m = 0; m < 4; ++m)
#pragma unroll
    for (int n = 0; n < 4; ++n)
#pragma unroll
      for (int j = 0; j < 4; ++j) {
        int r = crow + m * 16 + j;
        int c = ccol + n * 16;
        if (r < validM && c < validN) {
          float v = acc[m][n][j];
          if (bias) v += bias[c];
          if (C32) C32[cb + (long)r * ldc + c] = v;
          else     C16[cb + (long)r * ldc + c] = f2bf(v);
        }
      }
}

// scores layout: [row=b*4096+s][640] with col = h*77+t (cols 616..639 pad, never read).
// One wave per (row, h): softmax over 77, write bf16 probs; h==7 waves zero pad cols.
__global__ __launch_bounds__(256) void softmax_kernel(const float* __restrict__ scores,
                                                      ushort* __restrict__ probs) {
  int g = blockIdx.x * 4 + (threadIdx.x >> 6);
  int lane = threadIdx.x & 63;
  int row = g >> 3, h = g & 7;
  const float* s = scores + (long)row * 640 + h * 77;
  float v0 = s[lane];
  float v1 = (lane < 13) ? s[64 + lane] : -1e30f;
  float m = fmaxf(v0, v1);
#pragma unroll
  for (int o = 32; o; o >>= 1) m = fmaxf(m, __shfl_xor(m, o));
  float e0 = __expf(v0 - m);
  float e1 = (lane < 13) ? __expf(v1 - m) : 0.f;
  float sum = e0 + e1;
#pragma unroll
  for (int o = 32; o; o >>= 1) sum += __shfl_xor(sum, o);
  float inv = 1.f / sum;
  ushort* p = probs + (long)row * 640 + h * 77;
  p[lane] = f2bf(e0 * inv);
  if (lane < 13) p[64 + lane] = f2bf(e1 * inv);
  if (h == 7 && lane >= 40) p[77 + (lane - 40)] = 0;  // cols 616..639 := 0
}

// Nt[b][j][616..639] := 0 (pad K-columns of the output GEMM's B operand)
__global__ void zero_nt_pad(ushort* __restrict__ Nt) {
  int idx = blockIdx.x * 256 + threadIdx.x;
  if (idx >= 8 * 1280 * 24) return;
  int b = idx / (1280 * 24);
  int rem = idx % (1280 * 24);
  int j = rem / 24, t = rem % 24;
  Nt[(long)b * 1280 * 640 + (long)j * 640 + 616 + t] = 0;
}

extern "C" void kernel_launch(void* const* d_in, const int* in_sizes, int n_in,
                              void* d_out, int out_size, void* d_ws, size_t ws_size,
                              hipStream_t stream) {
  (void)in_sizes; (void)n_in; (void)out_size; (void)ws_size;
  const float* hs     = (const float*)d_in[0];
  const float* ehs    = (const float*)d_in[1];
  const float* Wq     = (const float*)d_in[2];
  const float* Wk     = (const float*)d_in[3];
  const float* Wv     = (const float*)d_in[4];
  const float* Wo     = (const float*)d_in[5];
  const float* bo     = (const float*)d_in[6];
  const float* q_down = (const float*)d_in[7];
  const float* q_up   = (const float*)d_in[8];
  const float* k_down = (const float*)d_in[9];
  const float* k_up   = (const float*)d_in[10];
  const float* v_down = (const float*)d_in[11];
  const float* v_up   = (const float*)d_in[12];
  const float* o_down = (const float*)d_in[13];
  const float* o_up   = (const float*)d_in[14];

  char* w = (char*)d_ws;
  size_t off = 0;
  auto alloc = [&](size_t b) { char* p = w + off; off = (off + b + 255) & ~(size_t)255; return p; };
  ushort* hs_bf  = (ushort*)alloc(32768L * 1280 * 2);  // reused as probs after G5
  ushort* ehs_bf = (ushort*)alloc(616L * 768 * 2);
  ushort* WqT    = (ushort*)alloc(1280L * 1280 * 2);   // Wq_eff^T * inv_sqrt(DH)
  ushort* Wk_bf  = (ushort*)alloc(1280L * 768 * 2);
  ushort* Wv_bf  = (ushort*)alloc(1280L * 768 * 2);
  ushort* Wo_bf  = (ushort*)alloc(1280L * 1280 * 2);
  ushort* k_bf   = (ushort*)alloc(616L * 1280 * 2);
  ushort* v_bf   = (ushort*)alloc(616L * 1280 * 2);
  ushort* Mt     = (ushort*)alloc(8L * 640 * 1280 * 2);
  ushort* Nt     = (ushort*)alloc(8L * 1280 * 640 * 2);
  float*  scores = (float*)alloc(32768L * 640 * 4);
  ushort* probs  = hs_bf;
  float*  outp   = (float*)d_out;
  const float invs = 0.07905694150420949f;  // 1/sqrt(160)

  // fold LoRA into effective weights (bf16)
  fold_kernel<<<6400, 256, 0, stream>>>(Wq, q_up, q_down, WqT, 1280, 1280, 1, invs);
  fold_kernel<<<3840, 256, 0, stream>>>(Wk, k_up, k_down, Wk_bf, 1280, 768, 0, 1.0f);
  fold_kernel<<<3840, 256, 0, stream>>>(Wv, v_up, v_down, Wv_bf, 1280, 768, 0, 1.0f);
  fold_kernel<<<6400, 256, 0, stream>>>(Wo, o_up, o_down, Wo_bf, 1280, 1280, 0, 1.0f);
  // f32 -> bf16
  cvt_kernel<<<20480, 256, 0, stream>>>(hs, hs_bf, 5242880);
  cvt_kernel<<<231, 256, 0, stream>>>(ehs, ehs_bf, 59136);
  // k, v projections: (616x768)@(768->1280), bf16 out
  gemm_bt<<<dim3(5, 10, 1), 256, 0, stream>>>(ehs_bf, 0, 0, 768, 616,
      Wk_bf, 0, 0, 768, 1280, nullptr, k_bf, 0, 0, 1280, nullptr, 768);
  gemm_bt<<<dim3(5, 10, 1), 256, 0, stream>>>(ehs_bf, 0, 0, 768, 616,
      Wv_bf, 0, 0, 768, 1280, nullptr, v_bf, 0, 0, 1280, nullptr, 768);
  // Mt[b][h*77+t][i] = inv_sqrt * sum_d k[b,t,h*160+d] * Wq_eff[h*160+d][i]   (z = b*8+h)
  gemm_bt<<<dim3(1, 10, 64), 256, 0, stream>>>(k_bf, 77L * 1280, 160, 1280, 77,
      WqT, 0, 160, 1280, 1280, nullptr, Mt, 640L * 1280, 77L * 1280, 1280, nullptr, 160);
  // Nt[b][j][h*77+t] = sum_d Wo_eff[j][h*160+d] * v[b,t,h*160+d]
  gemm_bt<<<dim3(10, 1, 64), 256, 0, stream>>>(Wo_bf, 0, 160, 1280, 1280,
      v_bf, 77L * 1280, 160, 1280, 77, nullptr, Nt, 1280L * 640, 77, 640, nullptr, 160);
  zero_nt_pad<<<960, 256, 0, stream>>>(Nt);
  // scores = hs_bf @ Mt^T : (8 x 4096 x 1280) @ (1280 -> 640), f32 out
  gemm_bt<<<dim3(32, 5, 8), 256, 0, stream>>>(hs_bf, 0, 4096L * 1280, 1280, 4096,
      Mt, 0, 640L * 1280, 1280, 640, scores, nullptr, 0, 4096L * 640, 640, nullptr, 1280);
  // softmax over each 77-wide head segment -> bf16 probs (aliases hs_bf region)
  softmax_kernel<<<65536, 256, 0, stream>>>(scores, probs);
  // out = probs @ Nt^T + bo : (8 x 4096 x 640) @ (640 -> 1280), f32 out
  gemm_bt<<<dim3(32, 10, 8), 256, 0, stream>>>(probs, 0, 4096L * 640, 640, 4096,
      Nt, 0, 1280L * 640, 640, 1280, outp, nullptr, 0, 4096L * 1280, 1280, bo, 640);
}

// Round 2
// 423.740 us; speedup vs baseline: 1.0086x; 1.0086x over previous
//
#include <hip/hip_runtime.h>
#include <hip/hip_bf16.h>
#include <stdint.h>

typedef short bf16x8 __attribute__((ext_vector_type(8)));
typedef float f32x4 __attribute__((ext_vector_type(4)));

#define DEVI static __device__ __forceinline__

DEVI ushort f2bf(float f) {
  union { float f; uint32_t u; } v; v.f = f;
  uint32_t u = v.u;
  return (ushort)((u + 0x7fffu + ((u >> 16) & 1u)) >> 16);
}

DEVI void gload16(const void* g, void* l) {
  __builtin_amdgcn_global_load_lds((const __attribute__((address_space(1))) void*)g,
                                   (__attribute__((address_space(3))) void*)l,
                                   16, 0, 0);
}

// ---------------- weight fold / convert (unchanged) ----------------

__global__ void fold_kernel(const float* __restrict__ W, const float* __restrict__ up,
                            const float* __restrict__ down, ushort* __restrict__ out,
                            int OUT, int IN, int transpose, float scale) {
  int idx = blockIdx.x * 256 + threadIdx.x;
  if (idx >= OUT * IN) return;
  int o = idx / IN, i = idx % IN;
  float v = W[idx];
#pragma unroll
  for (int r = 0; r < 4; ++r) v += up[o * 4 + r] * down[r * IN + i];
  v *= scale;
  out[transpose ? ((long)i * OUT + o) : idx] = f2bf(v);
}

__global__ void cvt_kernel(const float* __restrict__ in, ushort* __restrict__ out, int n8) {
  int idx = blockIdx.x * 256 + threadIdx.x;
  if (idx >= n8) return;
  const float4* p = (const float4*)(in + (long)idx * 8);
  float4 a = p[0], b = p[1];
  union { ushort us[8]; uint4 v; } r;
  r.us[0] = f2bf(a.x); r.us[1] = f2bf(a.y); r.us[2] = f2bf(a.z); r.us[3] = f2bf(a.w);
  r.us[4] = f2bf(b.x); r.us[5] = f2bf(b.y); r.us[6] = f2bf(b.z); r.us[7] = f2bf(b.w);
  *(uint4*)(out + (long)idx * 8) = r.v;
}

// ---------------- small-GEMM kernel (128x128, BK=32) — unchanged ----------------

__global__ __launch_bounds__(256) void gemm_bt(
    const ushort* __restrict__ A, long sA0, long sA1, int lda, int validM,
    const ushort* __restrict__ B, long sB0, long sB1, int ldb, int validN,
    float* __restrict__ C32, ushort* __restrict__ C16, long sC0, long sC1, int ldc,
    const float* __restrict__ bias, int K)
{
  __shared__ ushort As[128 * 32];
  __shared__ ushort Bs[128 * 32];

  const int z = blockIdx.z;
  const ushort* Ab = A + (long)(z >> 3) * sA0 + (long)(z & 7) * sA1;
  const ushort* Bb = B + (long)(z >> 3) * sB0 + (long)(z & 7) * sB1;
  const int m0 = blockIdx.x * 128;
  const int n0 = blockIdx.y * 128;
  const int tid = threadIdx.x;
  const int lane = tid & 63;
  const int wid = tid >> 6;

  const int c0 = tid;
  const int arow0 = min(m0 + (c0 >> 2), validM - 1);
  const int arow1 = min(m0 + (c0 >> 2) + 64, validM - 1);
  const int brow0 = min(n0 + (c0 >> 2), validN - 1);
  const int brow1 = min(n0 + (c0 >> 2) + 64, validN - 1);
  const int seg = (c0 & 3) * 8;

  const int wr = (wid >> 1) * 64;
  const int wc = (wid & 1) * 64;
  const int frow = lane & 15;
  const int fk = (lane >> 4) * 8;

  f32x4 acc[4][4] = {};

  for (int kt = 0; kt < K; kt += 32) {
    gload16(Ab + (long)arow0 * lda + kt + seg, As + c0 * 8);
    gload16(Ab + (long)arow1 * lda + kt + seg, As + (c0 + 256) * 8);
    gload16(Bb + (long)brow0 * ldb + kt + seg, Bs + c0 * 8);
    gload16(Bb + (long)brow1 * ldb + kt + seg, Bs + (c0 + 256) * 8);
    __syncthreads();

    bf16x8 af[4], bfr[4];
#pragma unroll
    for (int m = 0; m < 4; ++m)
      af[m] = *(const bf16x8*)(As + (wr + m * 16 + frow) * 32 + fk);
#pragma unroll
    for (int n = 0; n < 4; ++n)
      bfr[n] = *(const bf16x8*)(Bs + (wc + n * 16 + frow) * 32 + fk);
#pragma unroll
    for (int m = 0; m < 4; ++m)
#pragma unroll
      for (int n = 0; n < 4; ++n)
        acc[m][n] = __builtin_amdgcn_mfma_f32_16x16x32_bf16(af[m], bfr[n], acc[m][n], 0, 0, 0);
    __syncthreads();
  }

  const long cb = (long)(z >> 3) * sC0 + (long)(z & 7) * sC1;
  const int crow = m0 + wr + (lane >> 4) * 4;
  const int ccol = n0 + wc + (lane & 15);
#pragma unroll
  for (int m = 0; m < 4; ++m)
#pragma unroll
    for (int n = 0; n < 4; ++n)
#pragma unroll
      for (int j = 0; j < 4; ++j) {
        int r = crow + m * 16 + j;
        int c = ccol + n * 16;
        if (r < validM && c < validN) {
          float v = acc[m][n][j];
          if (bias) v += bias[c];
          if (C32) C32[cb + (long)r * ldc + c] = v;
          else     C16[cb + (long)r * ldc + c] = f2bf(v);
        }
      }
}

// ---------------- big GEMM: 256x256 tile, BK=64, 8 waves, dbuf + counted vmcnt ----------------
// C[m][n] = sum_k A[m][k]*B[n][k], A:[M][K] bf16, B:[N][K] bf16, C f32 (+bias).
// LDS layout per buffer: A[256][64] then B[256][64], 16B chunks XOR-swizzled:
//   logical chunk (row r, slot s in 0..7) stored at LDS slot s^(r&7).
// global_load_lds writes linearly; source address carries the inverse permutation.
__global__ __launch_bounds__(512, 2) void gemm256(
    const ushort* __restrict__ A, long sA, int lda, int validM,
    const ushort* __restrict__ B, long sB, int ldb, int validN,
    float* __restrict__ C, long sC, int ldc,
    const float* __restrict__ bias, int K)
{
  __shared__ ushort lds[65536];  // 128 KiB: [buf][A 16384 | B 16384] ushorts

  const int z = blockIdx.z;
  const ushort* Ab = A + (long)z * sA;
  const ushort* Bb = B + (long)z * sB;
  const int m0 = blockIdx.x * 256;
  const int n0 = blockIdx.y * 256;
  const int tid = threadIdx.x;
  const int lane = tid & 63;
  const int wid = tid >> 6;          // 0..7
  const int wr = wid >> 2;           // 0..1  (M half)
  const int wc = wid & 3;            // 0..3  (N quarter)

  // staging constants: call j covers rows (wid*4+j)*8 + (lane>>3), slot lane&7
  const int w4 = wid * 4;
  const int rr = lane >> 3;                       // 0..7
  const int sK = (((lane & 7) ^ rr) * 8);         // inverse-swizzled k-offset (elems)
  // fragment-read constants
  const int rowA = wr * 128 + (lane & 15);
  const int rowB = wc * 64 + (lane & 15);
  const int kslot = lane >> 4;                    // 0..3
  const int kxor = lane & 7;

  f32x4 acc[8][4] = {};

  const int NT = K >> 6;

#define STAGE256(bufOff, kt)                                                        \
  _Pragma("unroll")                                                                 \
  for (int j = 0; j < 4; ++j) {                                                     \
    int ra = min(m0 + (w4 + j) * 8 + rr, validM - 1);                               \
    int rb = min(n0 + (w4 + j) * 8 + rr, validN - 1);                               \
    gload16(Ab + (long)ra * lda + (kt) + sK, &lds[(bufOff) + (w4 + j) * 512]);      \
    gload16(Bb + (long)rb * ldb + (kt) + sK, &lds[(bufOff) + 16384 + (w4 + j) * 512]); \
  }

  STAGE256(0, 0);

  for (int t = 0; t < NT; ++t) {
    const int kt = t << 6;
    const int bufOff = (t & 1) << 15;   // 0 or 32768
    if (t + 1 < NT) {
      STAGE256(bufOff ^ 32768, kt + 64);
      asm volatile("s_waitcnt vmcnt(8)" ::: "memory");
    } else {
      asm volatile("s_waitcnt vmcnt(0)" ::: "memory");
    }
    __builtin_amdgcn_sched_barrier(0);
    __builtin_amdgcn_s_barrier();
    __builtin_amdgcn_sched_barrier(0);

#pragma unroll
    for (int kk = 0; kk < 2; ++kk) {
      bf16x8 af[8], bfv[4];
#pragma unroll
      for (int m = 0; m < 8; ++m)
        af[m] = *(const bf16x8*)(&lds[bufOff + (rowA + m * 16) * 64 +
                                      (((kk * 4 + kslot) ^ kxor) * 8)]);
#pragma unroll
      for (int n = 0; n < 4; ++n)
        bfv[n] = *(const bf16x8*)(&lds[bufOff + 16384 + (rowB + n * 16) * 64 +
                                       (((kk * 4 + kslot) ^ kxor) * 8)]);
      __builtin_amdgcn_s_setprio(1);
#pragma unroll
      for (int m = 0; m < 8; ++m)
#pragma unroll
        for (int n = 0; n < 4; ++n)
          acc[m][n] = __builtin_amdgcn_mfma_f32_16x16x32_bf16(af[m], bfv[n], acc[m][n], 0, 0, 0);
      __builtin_amdgcn_s_setprio(0);
    }
    __builtin_amdgcn_sched_barrier(0);
    __builtin_amdgcn_s_barrier();
  }

  const long cb = (long)z * sC;
  const int crow = m0 + wr * 128 + (lane >> 4) * 4;
  const int ccol = n0 + wc * 64 + (lane & 15);
#pragma unroll
  for (int m = 0; m < 8; ++m)
#pragma unroll
    for (int n = 0; n < 4; ++n) {
      int c = ccol + n * 16;
      if (c >= validN) continue;
      float bv = bias ? bias[c] : 0.f;
#pragma unroll
      for (int j = 0; j < 4; ++j) {
        int r = crow + m * 16 + j;
        if (r < validM) C[cb + (long)r * ldc + c] = acc[m][n][j] + bv;
      }
    }
#undef STAGE256
}

// ---------------- softmax over 77-wide head segments (unchanged) ----------------

__global__ __launch_bounds__(256) void softmax_kernel(const float* __restrict__ scores,
                                                      ushort* __restrict__ probs) {
  int g = blockIdx.x * 4 + (threadIdx.x >> 6);
  int lane = threadIdx.x & 63;
  int row = g >> 3, h = g & 7;
  const float* s = scores + (long)row * 640 + h * 77;
  float v0 = s[lane];
  float v1 = (lane < 13) ? s[64 + lane] : -1e30f;
  float m = fmaxf(v0, v1);
#pragma unroll
  for (int o = 32; o; o >>= 1) m = fmaxf(m, __shfl_xor(m, o));
  float e0 = __expf(v0 - m);
  float e1 = (lane < 13) ? __expf(v1 - m) : 0.f;
  float sum = e0 + e1;
#pragma unroll
  for (int o = 32; o; o >>= 1) sum += __shfl_xor(sum, o);
  float inv = 1.f / sum;
  ushort* p = probs + (long)row * 640 + h * 77;
  p[lane] = f2bf(e0 * inv);
  if (lane < 13) p[64 + lane] = f2bf(e1 * inv);
  if (h == 7 && lane >= 40) p[77 + (lane - 40)] = 0;  // cols 616..639 := 0
}

__global__ void zero_nt_pad(ushort* __restrict__ Nt) {
  int idx = blockIdx.x * 256 + threadIdx.x;
  if (idx >= 8 * 1280 * 24) return;
  int b = idx / (1280 * 24);
  int rem = idx % (1280 * 24);
  int j = rem / 24, t = rem % 24;
  Nt[(long)b * 1280 * 640 + (long)j * 640 + 616 + t] = 0;
}

extern "C" void kernel_launch(void* const* d_in, const int* in_sizes, int n_in,
                              void* d_out, int out_size, void* d_ws, size_t ws_size,
                              hipStream_t stream) {
  (void)in_sizes; (void)n_in; (void)out_size; (void)ws_size;
  const float* hs     = (const float*)d_in[0];
  const float* ehs    = (const float*)d_in[1];
  const float* Wq     = (const float*)d_in[2];
  const float* Wk     = (const float*)d_in[3];
  const float* Wv     = (const float*)d_in[4];
  const float* Wo     = (const float*)d_in[5];
  const float* bo     = (const float*)d_in[6];
  const float* q_down = (const float*)d_in[7];
  const float* q_up   = (const float*)d_in[8];
  const float* k_down = (const float*)d_in[9];
  const float* k_up   = (const float*)d_in[10];
  const float* v_down = (const float*)d_in[11];
  const float* v_up   = (const float*)d_in[12];
  const float* o_down = (const float*)d_in[13];
  const float* o_up   = (const float*)d_in[14];

  char* w = (char*)d_ws;
  size_t off = 0;
  auto alloc = [&](size_t b) { char* p = w + off; off = (off + b + 255) & ~(size_t)255; return p; };
  ushort* hs_bf  = (ushort*)alloc(32768L * 1280 * 2);  // reused as probs after scores GEMM
  ushort* ehs_bf = (ushort*)alloc(616L * 768 * 2);
  ushort* WqT    = (ushort*)alloc(1280L * 1280 * 2);   // Wq_eff^T * inv_sqrt(DH)
  ushort* Wk_bf  = (ushort*)alloc(1280L * 768 * 2);
  ushort* Wv_bf  = (ushort*)alloc(1280L * 768 * 2);
  ushort* Wo_bf  = (ushort*)alloc(1280L * 1280 * 2);
  ushort* k_bf   = (ushort*)alloc(616L * 1280 * 2);
  ushort* v_bf   = (ushort*)alloc(616L * 1280 * 2);
  ushort* Mt     = (ushort*)alloc(8L * 640 * 1280 * 2);
  ushort* Nt     = (ushort*)alloc(8L * 1280 * 640 * 2);
  float*  scores = (float*)alloc(32768L * 640 * 4);
  ushort* probs  = hs_bf;
  float*  outp   = (float*)d_out;
  const float invs = 0.07905694150420949f;  // 1/sqrt(160)

  // fold LoRA into effective weights (bf16)
  fold_kernel<<<6400, 256, 0, stream>>>(Wq, q_up, q_down, WqT, 1280, 1280, 1, invs);
  fold_kernel<<<3840, 256, 0, stream>>>(Wk, k_up, k_down, Wk_bf, 1280, 768, 0, 1.0f);
  fold_kernel<<<3840, 256, 0, stream>>>(Wv, v_up, v_down, Wv_bf, 1280, 768, 0, 1.0f);
  fold_kernel<<<6400, 256, 0, stream>>>(Wo, o_up, o_down, Wo_bf, 1280, 1280, 0, 1.0f);
  // f32 -> bf16
  cvt_kernel<<<20480, 256, 0, stream>>>(hs, hs_bf, 5242880);
  cvt_kernel<<<231, 256, 0, stream>>>(ehs, ehs_bf, 59136);
  // k, v projections: (616x768)@(768->1280), bf16 out
  gemm_bt<<<dim3(5, 10, 1), 256, 0, stream>>>(ehs_bf, 0, 0, 768, 616,
      Wk_bf, 0, 0, 768, 1280, nullptr, k_bf, 0, 0, 1280, nullptr, 768);
  gemm_bt<<<dim3(5, 10, 1), 256, 0, stream>>>(ehs_bf, 0, 0, 768, 616,
      Wv_bf, 0, 0, 768, 1280, nullptr, v_bf, 0, 0, 1280, nullptr, 768);
  // Mt[b][h*77+t][i] = inv_sqrt * sum_d k[b,t,h*160+d] * Wq_eff[h*160+d][i]   (z = b*8+h)
  gemm_bt<<<dim3(1, 10, 64), 256, 0, stream>>>(k_bf, 77L * 1280, 160, 1280, 77,
      WqT, 0, 160, 1280, 1280, nullptr, Mt, 640L * 1280, 77L * 1280, 1280, nullptr, 160);
  // Nt[b][j][h*77+t] = sum_d Wo_eff[j][h*160+d] * v[b,t,h*160+d]
  gemm_bt<<<dim3(10, 1, 64), 256, 0, stream>>>(Wo_bf, 0, 160, 1280, 1280,
      v_bf, 77L * 1280, 160, 1280, 77, nullptr, Nt, 1280L * 640, 77, 640, nullptr, 160);
  zero_nt_pad<<<960, 256, 0, stream>>>(Nt);
  // scores = hs_bf @ Mt^T : per batch (4096 x 1280) @ (1280 -> 640 pad 768), f32 out
  gemm256<<<dim3(16, 3, 8), 512, 0, stream>>>(hs_bf, 4096L * 1280, 1280, 4096,
      Mt, 640L * 1280, 1280, 640, scores, 4096L * 640, 640, nullptr, 1280);
  // softmax over each 77-wide head segment -> bf16 probs (aliases hs_bf region)
  softmax_kernel<<<65536, 256, 0, stream>>>(scores, probs);
  // out = probs @ Nt^T + bo : per batch (4096 x 640) @ (640 -> 1280), f32 out
  gemm256<<<dim3(16, 5, 8), 512, 0, stream>>>(probs, 4096L * 640, 640, 4096,
      Nt, 1280L * 640, 640, 1280, outp, 4096L * 1280, 1280, bo, 640);
}

// Round 3
// 396.613 us; speedup vs baseline: 1.0776x; 1.0684x over previous
//
#include <hip/hip_runtime.h>
#include <hip/hip_bf16.h>
#include <stdint.h>

typedef short bf16x8 __attribute__((ext_vector_type(8)));
typedef float f32x4 __attribute__((ext_vector_type(4)));

#define DEVI static __device__ __forceinline__

DEVI ushort f2bf(float f) {
  union { float f; uint32_t u; } v; v.f = f;
  uint32_t u = v.u;
  return (ushort)((u + 0x7fffu + ((u >> 16) & 1u)) >> 16);
}

DEVI void gload16(const void* g, void* l) {
  __builtin_amdgcn_global_load_lds((const __attribute__((address_space(1))) void*)g,
                                   (__attribute__((address_space(3))) void*)l,
                                   16, 0, 0);
}

#define SB() __builtin_amdgcn_sched_barrier(0)

// ---------------- weight fold / convert ----------------

__global__ void fold_kernel(const float* __restrict__ W, const float* __restrict__ up,
                            const float* __restrict__ down, ushort* __restrict__ out,
                            int OUT, int IN, int transpose, float scale) {
  int idx = blockIdx.x * 256 + threadIdx.x;
  if (idx >= OUT * IN) return;
  int o = idx / IN, i = idx % IN;
  float v = W[idx];
#pragma unroll
  for (int r = 0; r < 4; ++r) v += up[o * 4 + r] * down[r * IN + i];
  v *= scale;
  out[transpose ? ((long)i * OUT + o) : idx] = f2bf(v);
}

__global__ void cvt_kernel(const float* __restrict__ in, ushort* __restrict__ out, int n8) {
  int idx = blockIdx.x * 256 + threadIdx.x;
  if (idx >= n8) return;
  const float4* p = (const float4*)(in + (long)idx * 8);
  float4 a = p[0], b = p[1];
  union { ushort us[8]; uint4 v; } r;
  r.us[0] = f2bf(a.x); r.us[1] = f2bf(a.y); r.us[2] = f2bf(a.z); r.us[3] = f2bf(a.w);
  r.us[4] = f2bf(b.x); r.us[5] = f2bf(b.y); r.us[6] = f2bf(b.z); r.us[7] = f2bf(b.w);
  *(uint4*)(out + (long)idx * 8) = r.v;
}

// ---------------- small-GEMM kernel (128x128, BK=32) ----------------

__global__ __launch_bounds__(256) void gemm_bt(
    const ushort* __restrict__ A, long sA0, long sA1, int lda, int validM,
    const ushort* __restrict__ B, long sB0, long sB1, int ldb, int validN,
    float* __restrict__ C32, ushort* __restrict__ C16, long sC0, long sC1, int ldc,
    const float* __restrict__ bias, int K)
{
  __shared__ ushort As[128 * 32];
  __shared__ ushort Bs[128 * 32];

  const int z = blockIdx.z;
  const ushort* Ab = A + (long)(z >> 3) * sA0 + (long)(z & 7) * sA1;
  const ushort* Bb = B + (long)(z >> 3) * sB0 + (long)(z & 7) * sB1;
  const int m0 = blockIdx.x * 128;
  const int n0 = blockIdx.y * 128;
  const int tid = threadIdx.x;
  const int lane = tid & 63;
  const int wid = tid >> 6;

  const int c0 = tid;
  const int arow0 = min(m0 + (c0 >> 2), validM - 1);
  const int arow1 = min(m0 + (c0 >> 2) + 64, validM - 1);
  const int brow0 = min(n0 + (c0 >> 2), validN - 1);
  const int brow1 = min(n0 + (c0 >> 2) + 64, validN - 1);
  const int seg = (c0 & 3) * 8;

  const int wr = (wid >> 1) * 64;
  const int wc = (wid & 1) * 64;
  const int frow = lane & 15;
  const int fk = (lane >> 4) * 8;

  f32x4 acc[4][4] = {};

  for (int kt = 0; kt < K; kt += 32) {
    gload16(Ab + (long)arow0 * lda + kt + seg, As + c0 * 8);
    gload16(Ab + (long)arow1 * lda + kt + seg, As + (c0 + 256) * 8);
    gload16(Bb + (long)brow0 * ldb + kt + seg, Bs + c0 * 8);
    gload16(Bb + (long)brow1 * ldb + kt + seg, Bs + (c0 + 256) * 8);
    __syncthreads();

    bf16x8 af[4], bfr[4];
#pragma unroll
    for (int m = 0; m < 4; ++m)
      af[m] = *(const bf16x8*)(As + (wr + m * 16 + frow) * 32 + fk);
#pragma unroll
    for (int n = 0; n < 4; ++n)
      bfr[n] = *(const bf16x8*)(Bs + (wc + n * 16 + frow) * 32 + fk);
#pragma unroll
    for (int m = 0; m < 4; ++m)
#pragma unroll
      for (int n = 0; n < 4; ++n)
        acc[m][n] = __builtin_amdgcn_mfma_f32_16x16x32_bf16(af[m], bfr[n], acc[m][n], 0, 0, 0);
    __syncthreads();
  }

  const long cb = (long)(z >> 3) * sC0 + (long)(z & 7) * sC1;
  const int crow = m0 + wr + (lane >> 4) * 4;
  const int ccol = n0 + wc + (lane & 15);
#pragma unroll
  for (int m = 0; m < 4; ++m)
#pragma unroll
    for (int n = 0; n < 4; ++n)
#pragma unroll
      for (int j = 0; j < 4; ++j) {
        int r = crow + m * 16 + j;
        int c = ccol + n * 16;
        if (r < validM && c < validN) {
          float v = acc[m][n][j];
          if (bias) v += bias[c];
          if (C32) C32[cb + (long)r * ldc + c] = v;
          else     C16[cb + (long)r * ldc + c] = f2bf(v);
        }
      }
}

// ---------------- big GEMM: 256x256, BK=32, ring-4 LDS, counted vmcnt ----------------
// C[m][n] = sum_k A[m][k]*B[n][k]. LDS: 4 K-tile buffers x (A 16KB | B 16KB) = 128 KiB.
// While computing tile t (buf t&3), stage tile t+3 (buf (t+3)&3 — free since t-1 done).
// 16B chunk (row r, logical slot s in 0..3) stored at physical slot s^((r>>1)&3);
// global_load_lds dest linear, source carries the inverse permutation (same involution).
__global__ __launch_bounds__(512, 2) void gemm256(
    const ushort* __restrict__ A, long sA, int lda, int validM,
    const ushort* __restrict__ B, long sB, int ldb, int validN,
    float* __restrict__ C, long sC, int ldc,
    const float* __restrict__ bias, int K)
{
  __shared__ ushort lds[65536];  // 4 bufs * 16384 ushorts (A 8192 | B 8192)

  const int z = blockIdx.z;
  const ushort* Ab = A + (long)z * sA;
  const ushort* Bb = B + (long)z * sB;
  const int m0 = blockIdx.x * 256;
  const int n0 = blockIdx.y * 256;
  const int tid = threadIdx.x;
  const int lane = tid & 63;
  const int wid = tid >> 6;          // 0..7
  const int wr = wid >> 2;           // 0..1  (M half)
  const int wc = wid & 3;            // 0..3  (N quarter)

  // staging: thread stages chunks tid (rows 0..127) and tid+512 (rows 128..255)
  // of A and B per tile. chunk c: row=c>>2, phys slot=c&3, logical slot=(c&3)^((c>>3)&3).
  const int r0 = tid >> 2;
  const int s0 = ((tid & 3) ^ ((tid >> 3) & 3)) * 8;   // same key for r0 and r0+128
  const long aoff0 = (long)min(m0 + r0, validM - 1) * lda + s0;
  const long aoff1 = (long)min(m0 + r0 + 128, validM - 1) * lda + s0;
  const long boff0 = (long)min(n0 + r0, validN - 1) * ldb + s0;
  const long boff1 = (long)min(n0 + r0 + 128, validN - 1) * ldb + s0;
  const int d0 = tid * 8;           // LDS ushort index of chunk tid
  const int d1 = tid * 8 + 4096;    // chunk tid+512

  // fragment-read offsets (ushort index within a buffer)
  int afoff[8], bfoff[4];
#pragma unroll
  for (int m = 0; m < 8; ++m) {
    int r = wr * 128 + (lane & 15) + m * 16;
    afoff[m] = r * 32 + (((lane >> 4) ^ ((r >> 1) & 3)) * 8);
  }
#pragma unroll
  for (int n = 0; n < 4; ++n) {
    int r = wc * 64 + (lane & 15) + n * 16;
    bfoff[n] = 8192 + r * 32 + (((lane >> 4) ^ ((r >> 1) & 3)) * 8);
  }

  f32x4 acc[8][4] = {};
  const int NT = K >> 5;

#define STAGE_H0(tt) { int sb = ((tt) & 3) << 14; int pk = (tt) << 5; \
    gload16(Ab + aoff0 + pk, &lds[sb + d0]); \
    gload16(Bb + boff0 + pk, &lds[sb + 8192 + d0]); }
#define STAGE_H1(tt) { int sb = ((tt) & 3) << 14; int pk = (tt) << 5; \
    gload16(Ab + aoff1 + pk, &lds[sb + d1]); \
    gload16(Bb + boff1 + pk, &lds[sb + 8192 + d1]); }

  // prologue: stage tiles 0,1,2 (NT >= 20 always here)
  STAGE_H0(0) STAGE_H1(0)
  STAGE_H0(1) STAGE_H1(1)
  STAGE_H0(2) STAGE_H1(2)
  asm volatile("s_waitcnt vmcnt(8)" ::: "memory");  // tile 0 resident (1,2 in flight)
  SB(); __builtin_amdgcn_s_barrier(); SB();

  for (int t = 0; t < NT; ++t) {
    const int base = (t & 3) << 14;
    const bool pre = (t + 3 < NT);

    // ---- phase 0: read m0-3 + B fragments, stage half 0 of t+3
    bf16x8 af0[4], af1[4], bfv[4];
#pragma unroll
    for (int m = 0; m < 4; ++m) af0[m] = *(const bf16x8*)(&lds[base + afoff[m]]);
#pragma unroll
    for (int n = 0; n < 4; ++n) bfv[n] = *(const bf16x8*)(&lds[base + bfoff[n]]);
    if (pre) STAGE_H0(t + 3)
    SB(); __builtin_amdgcn_s_barrier(); SB();
    __builtin_amdgcn_s_setprio(1);
#pragma unroll
    for (int m = 0; m < 4; ++m)
#pragma unroll
      for (int n = 0; n < 4; ++n)
        acc[m][n] = __builtin_amdgcn_mfma_f32_16x16x32_bf16(af0[m], bfv[n], acc[m][n], 0, 0, 0);
    __builtin_amdgcn_s_setprio(0);
    SB(); __builtin_amdgcn_s_barrier(); SB();

    // ---- phase 1: read m4-7 fragments, stage half 1 of t+3, counted vmcnt
    #pragma unroll
    for (int m = 0; m < 4; ++m) af1[m] = *(const bf16x8*)(&lds[base + afoff[m + 4]]);
    if (pre) STAGE_H1(t + 3)
    if (t + 3 < NT)      { asm volatile("s_waitcnt vmcnt(8)" ::: "memory"); }
    else if (t + 2 < NT) { asm volatile("s_waitcnt vmcnt(4)" ::: "memory"); }
    else if (t + 1 < NT) { asm volatile("s_waitcnt vmcnt(0)" ::: "memory"); }
    SB(); __builtin_amdgcn_s_barrier(); SB();
    __builtin_amdgcn_s_setprio(1);
#pragma unroll
    for (int m = 4; m < 8; ++m)
#pragma unroll
      for (int n = 0; n < 4; ++n)
        acc[m][n] = __builtin_amdgcn_mfma_f32_16x16x32_bf16(af1[m - 4], bfv[n], acc[m][n], 0, 0, 0);
    __builtin_amdgcn_s_setprio(0);
    SB(); __builtin_amdgcn_s_barrier(); SB();
  }
#undef STAGE_H0
#undef STAGE_H1

  const long cb = (long)z * sC;
  const int crow = m0 + wr * 128 + (lane >> 4) * 4;
  const int ccol = n0 + wc * 64 + (lane & 15);
#pragma unroll
  for (int m = 0; m < 8; ++m)
#pragma unroll
    for (int n = 0; n < 4; ++n) {
      int c = ccol + n * 16;
      if (c >= validN) continue;
      float bv = bias ? bias[c] : 0.f;
#pragma unroll
      for (int j = 0; j < 4; ++j) {
        int r = crow + m * 16 + j;
        if (r < validM) C[cb + (long)r * ldc + c] = acc[m][n][j] + bv;
      }
    }
}

// ---------------- softmax over 77-wide head segments ----------------

__global__ __launch_bounds__(256) void softmax_kernel(const float* __restrict__ scores,
                                                      ushort* __restrict__ probs) {
  int g = blockIdx.x * 4 + (threadIdx.x >> 6);
  int lane = threadIdx.x & 63;
  int row = g >> 3, h = g & 7;
  const float* s = scores + (long)row * 640 + h * 77;
  float v0 = s[lane];
  float v1 = (lane < 13) ? s[64 + lane] : -1e30f;
  float m = fmaxf(v0, v1);
#pragma unroll
  for (int o = 32; o; o >>= 1) m = fmaxf(m, __shfl_xor(m, o));
  float e0 = __expf(v0 - m);
  float e1 = (lane < 13) ? __expf(v1 - m) : 0.f;
  float sum = e0 + e1;
#pragma unroll
  for (int o = 32; o; o >>= 1) sum += __shfl_xor(sum, o);
  float inv = 1.f / sum;
  ushort* p = probs + (long)row * 640 + h * 77;
  p[lane] = f2bf(e0 * inv);
  if (lane < 13) p[64 + lane] = f2bf(e1 * inv);
  if (h == 7 && lane >= 40) p[77 + (lane - 40)] = 0;  // cols 616..639 := 0
}

__global__ void zero_nt_pad(ushort* __restrict__ Nt) {
  int idx = blockIdx.x * 256 + threadIdx.x;
  if (idx >= 8 * 1280 * 24) return;
  int b = idx / (1280 * 24);
  int rem = idx % (1280 * 24);
  int j = rem / 24, t = rem % 24;
  Nt[(long)b * 1280 * 640 + (long)j * 640 + 616 + t] = 0;
}

extern "C" void kernel_launch(void* const* d_in, const int* in_sizes, int n_in,
                              void* d_out, int out_size, void* d_ws, size_t ws_size,
                              hipStream_t stream) {
  (void)in_sizes; (void)n_in; (void)out_size; (void)ws_size;
  const float* hs     = (const float*)d_in[0];
  const float* ehs    = (const float*)d_in[1];
  const float* Wq     = (const float*)d_in[2];
  const float* Wk     = (const float*)d_in[3];
  const float* Wv     = (const float*)d_in[4];
  const float* Wo     = (const float*)d_in[5];
  const float* bo     = (const float*)d_in[6];
  const float* q_down = (const float*)d_in[7];
  const float* q_up   = (const float*)d_in[8];
  const float* k_down = (const float*)d_in[9];
  const float* k_up   = (const float*)d_in[10];
  const float* v_down = (const float*)d_in[11];
  const float* v_up   = (const float*)d_in[12];
  const float* o_down = (const float*)d_in[13];
  const float* o_up   = (const float*)d_in[14];

  char* w = (char*)d_ws;
  size_t off = 0;
  auto alloc = [&](size_t b) { char* p = w + off; off = (off + b + 255) & ~(size_t)255; return p; };
  ushort* hs_bf  = (ushort*)alloc(32768L * 1280 * 2);  // reused as probs after scores GEMM
  ushort* ehs_bf = (ushort*)alloc(616L * 768 * 2);
  ushort* WqT    = (ushort*)alloc(1280L * 1280 * 2);   // Wq_eff^T * inv_sqrt(DH)
  ushort* Wkv    = (ushort*)alloc(2560L * 768 * 2);    // [Wk_eff; Wv_eff]
  ushort* Wo_bf  = (ushort*)alloc(1280L * 1280 * 2);
  ushort* kv_bf  = (ushort*)alloc(616L * 2560 * 2);    // k = cols 0..1279, v = cols 1280..2559
  ushort* Mt     = (ushort*)alloc(8L * 640 * 1280 * 2);
  ushort* Nt     = (ushort*)alloc(8L * 1280 * 640 * 2);
  float*  scores = (float*)alloc(32768L * 640 * 4);
  ushort* probs  = hs_bf;
  float*  outp   = (float*)d_out;
  const float invs = 0.07905694150420949f;  // 1/sqrt(160)

  // fold LoRA into effective weights (bf16)
  fold_kernel<<<6400, 256, 0, stream>>>(Wq, q_up, q_down, WqT, 1280, 1280, 1, invs);
  fold_kernel<<<3840, 256, 0, stream>>>(Wk, k_up, k_down, Wkv, 1280, 768, 0, 1.0f);
  fold_kernel<<<3840, 256, 0, stream>>>(Wv, v_up, v_down, Wkv + 1280L * 768, 1280, 768, 0, 1.0f);
  fold_kernel<<<6400, 256, 0, stream>>>(Wo, o_up, o_down, Wo_bf, 1280, 1280, 0, 1.0f);
  // f32 -> bf16
  cvt_kernel<<<20480, 256, 0, stream>>>(hs, hs_bf, 5242880);
  cvt_kernel<<<231, 256, 0, stream>>>(ehs, ehs_bf, 59136);
  // fused k|v projection: (616x768)@(768->2560), bf16 out
  gemm_bt<<<dim3(5, 20, 1), 256, 0, stream>>>(ehs_bf, 0, 0, 768, 616,
      Wkv, 0, 0, 768, 2560, nullptr, kv_bf, 0, 0, 2560, nullptr, 768);
  // Mt[b][h*77+t][i] = inv_sqrt * sum_d k[b,t,h*160+d] * Wq_eff[h*160+d][i]   (z = b*8+h)
  gemm_bt<<<dim3(1, 10, 64), 256, 0, stream>>>(kv_bf, 77L * 2560, 160, 2560, 77,
      WqT, 0, 160, 1280, 1280, nullptr, Mt, 640L * 1280, 77L * 1280, 1280, nullptr, 160);
  // Nt[b][j][h*77+t] = sum_d Wo_eff[j][h*160+d] * v[b,t,h*160+d]
  gemm_bt<<<dim3(10, 1, 64), 256, 0, stream>>>(Wo_bf, 0, 160, 1280, 1280,
      kv_bf + 1280, 77L * 2560, 160, 2560, 77, nullptr, Nt, 1280L * 640, 77, 640, nullptr, 160);
  zero_nt_pad<<<960, 256, 0, stream>>>(Nt);
  // scores = hs_bf @ Mt^T : per batch (4096 x 1280) @ (1280 -> 640 pad), f32 out
  gemm256<<<dim3(16, 3, 8), 512, 0, stream>>>(hs_bf, 4096L * 1280, 1280, 4096,
      Mt, 640L * 1280, 1280, 640, scores, 4096L * 640, 640, nullptr, 1280);
  // softmax over each 77-wide head segment -> bf16 probs (aliases hs_bf region)
  softmax_kernel<<<65536, 256, 0, stream>>>(scores, probs);
  // out = probs @ Nt^T + bo : per batch (4096 x 640) @ (640 -> 1280), f32 out
  gemm256<<<dim3(16, 5, 8), 512, 0, stream>>>(probs, 4096L * 640, 640, 4096,
      Nt, 1280L * 640, 640, 1280, outp, 4096L * 1280, 1280, bo, 640);
}

// Round 5
// 347.569 us; speedup vs baseline: 1.2297x; 1.1411x over previous
//
#include <hip/hip_runtime.h>
#include <hip/hip_bf16.h>
#include <stdint.h>

typedef short bf16x8 __attribute__((ext_vector_type(8)));
typedef float f32x4 __attribute__((ext_vector_type(4)));

#define DEVI static __device__ __forceinline__

DEVI ushort f2bf(float f) {
  union { float f; uint32_t u; } v; v.f = f;
  uint32_t u = v.u;
  return (ushort)((u + 0x7fffu + ((u >> 16) & 1u)) >> 16);
}

DEVI void gload16(const void* g, void* l) {
  __builtin_amdgcn_global_load_lds((const __attribute__((address_space(1))) void*)g,
                                   (__attribute__((address_space(3))) void*)l,
                                   16, 0, 0);
}

#define SBAR() __builtin_amdgcn_sched_barrier(0)
#define KEY(r) (((r) & 3) ^ (((r) >> 2) & 3))

// ---------------- weight fold / convert ----------------

__global__ void fold_kernel(const float* __restrict__ W, const float* __restrict__ up,
                            const float* __restrict__ down, ushort* __restrict__ out,
                            int OUT, int IN, int transpose, float scale) {
  int idx = blockIdx.x * 256 + threadIdx.x;
  if (idx >= OUT * IN) return;
  int o = idx / IN, i = idx % IN;
  float v = W[idx];
#pragma unroll
  for (int r = 0; r < 4; ++r) v += up[o * 4 + r] * down[r * IN + i];
  v *= scale;
  out[transpose ? ((long)i * OUT + o) : idx] = f2bf(v);
}

__global__ void cvt_kernel(const float* __restrict__ in, ushort* __restrict__ out, int n8) {
  int idx = blockIdx.x * 256 + threadIdx.x;
  if (idx >= n8) return;
  const float4* p = (const float4*)(in + (long)idx * 8);
  float4 a = p[0], b = p[1];
  union { ushort us[8]; uint4 v; } r;
  r.us[0] = f2bf(a.x); r.us[1] = f2bf(a.y); r.us[2] = f2bf(a.z); r.us[3] = f2bf(a.w);
  r.us[4] = f2bf(b.x); r.us[5] = f2bf(b.y); r.us[6] = f2bf(b.z); r.us[7] = f2bf(b.w);
  *(uint4*)(out + (long)idx * 8) = r.v;
}

// ---------------- small-GEMM kernel (128x128, BK=32) — proven ----------------

__global__ __launch_bounds__(256) void gemm_bt(
    const ushort* __restrict__ A, long sA0, long sA1, int lda, int validM,
    const ushort* __restrict__ B, long sB0, long sB1, int ldb, int validN,
    float* __restrict__ C32, ushort* __restrict__ C16, long sC0, long sC1, int ldc,
    const float* __restrict__ bias, int K)
{
  __shared__ ushort As[128 * 32];
  __shared__ ushort Bs[128 * 32];

  const int z = blockIdx.z;
  const ushort* Ab = A + (long)(z >> 3) * sA0 + (long)(z & 7) * sA1;
  const ushort* Bb = B + (long)(z >> 3) * sB0 + (long)(z & 7) * sB1;
  const int m0 = blockIdx.x * 128;
  const int n0 = blockIdx.y * 128;
  const int tid = threadIdx.x;
  const int lane = tid & 63;
  const int wid = tid >> 6;

  const int c0 = tid;
  const int arow0 = min(m0 + (c0 >> 2), validM - 1);
  const int arow1 = min(m0 + (c0 >> 2) + 64, validM - 1);
  const int brow0 = min(n0 + (c0 >> 2), validN - 1);
  const int brow1 = min(n0 + (c0 >> 2) + 64, validN - 1);
  const int seg = (c0 & 3) * 8;

  const int wr = (wid >> 1) * 64;
  const int wc = (wid & 1) * 64;
  const int frow = lane & 15;
  const int fk = (lane >> 4) * 8;

  f32x4 acc[4][4] = {};

  for (int kt = 0; kt < K; kt += 32) {
    gload16(Ab + (long)arow0 * lda + kt + seg, As + c0 * 8);
    gload16(Ab + (long)arow1 * lda + kt + seg, As + (c0 + 256) * 8);
    gload16(Bb + (long)brow0 * ldb + kt + seg, Bs + c0 * 8);
    gload16(Bb + (long)brow1 * ldb + kt + seg, Bs + (c0 + 256) * 8);
    __syncthreads();

    bf16x8 af[4], bfr[4];
#pragma unroll
    for (int m = 0; m < 4; ++m)
      af[m] = *(const bf16x8*)(As + (wr + m * 16 + frow) * 32 + fk);
#pragma unroll
    for (int n = 0; n < 4; ++n)
      bfr[n] = *(const bf16x8*)(Bs + (wc + n * 16 + frow) * 32 + fk);
#pragma unroll
    for (int m = 0; m < 4; ++m)
#pragma unroll
      for (int n = 0; n < 4; ++n)
        acc[m][n] = __builtin_amdgcn_mfma_f32_16x16x32_bf16(af[m], bfr[n], acc[m][n], 0, 0, 0);
    __syncthreads();
  }

  const long cb = (long)(z >> 3) * sC0 + (long)(z & 7) * sC1;
  const int crow = m0 + wr + (lane >> 4) * 4;
  const int ccol = n0 + wc + (lane & 15);
#pragma unroll
  for (int m = 0; m < 4; ++m)
#pragma unroll
    for (int n = 0; n < 4; ++n)
#pragma unroll
      for (int j = 0; j < 4; ++j) {
        int r = crow + m * 16 + j;
        int c = ccol + n * 16;
        if (r < validM && c < validN) {
          float v = acc[m][n][j];
          if (bias) v += bias[c];
          if (C32) C32[cb + (long)r * ldc + c] = v;
          else     C16[cb + (long)r * ldc + c] = f2bf(v);
        }
      }
}

// ---------------- fused scores GEMM + softmax ----------------
// Per block: 256 hs-rows x 2 heads (192 score cols, 96/head). z = batch.
// A = hs f32 (cvt to bf16 during staging via ds_write — per-lane scatter OK),
// B = Mt bf16 via gload16 (dest linear in lane, source pre-swizzled — rule #21).
// Waves: 4M x 2N -> wave = 64 rows x one head. Softmax wave-local over 77 cols.
// probs written bf16 at [b][s][h*80 + t] (t<77 real, 77..79 zero). 8*80 = 640.
__global__ __launch_bounds__(512, 2) void score_softmax(
    const float* __restrict__ hs, const ushort* __restrict__ Mt,
    ushort* __restrict__ probs)
{
  __shared__ ushort lds[45056];  // staging: 2 bufs x (A 8192 | B 6144) = 28672; bounce: 8 x 5632

  const int z = blockIdx.z;                 // batch
  const int s0 = blockIdx.x * 256;
  const int h0 = blockIdx.y * 2;
  const int tid = threadIdx.x;
  const int lane = tid & 63;
  const int wid = tid >> 6;
  const int wM = wid >> 1;                  // 0..3
  const int wN = wid & 1;                   // 0..1

  // ---- A staging (f32 -> bf16, swizzled ds_write). 256 rows x 32k, 2 chunks/thread.
  const int arow = tid >> 1;                         // 0..255
  const int akey = KEY(arow);
  const int sl0 = 2 * (tid & 1), sl1 = sl0 + 1;
  const float* ag = hs + ((long)z * 4096 + s0 + arow) * 1280;
  const int adst0 = arow * 32 + ((sl0 ^ akey) * 8);
  const int adst1 = arow * 32 + ((sl1 ^ akey) * 8);

  // ---- B staging (gload16, source-swizzled, dest linear). 192 rows x 32k = 768 chunks.
  const int br1 = tid >> 2;                          // 0..127
  const int br2 = 128 + (tid >> 2);                  // 128..191 (tid<256)
  const int bp = tid & 3;
  const ushort* MtB = Mt + (long)z * (640L * 1280);
  auto brow_src = [&](int rb) -> long {
    int hl = rb >= 96;
    int t = rb - 96 * hl;
    return (long)((h0 + hl) * 77 + min(t, 76)) * 1280;
  };
  const long bsrc1 = brow_src(br1) + ((bp ^ KEY(br1)) * 8);
  const long bsrc2 = brow_src(br2) + ((bp ^ KEY(br2)) * 8);
  const int bdst1 = tid * 8;         // chunk tid      (linear in lane)
  const int bdst2 = 4096 + tid * 8;  // chunk 512+tid  (linear in lane)

  // ---- fragment offsets
  const int kk = lane >> 4;
  int afoff[4], bfoff[6];
#pragma unroll
  for (int m = 0; m < 4; ++m) {
    int r = wM * 64 + m * 16 + (lane & 15);
    afoff[m] = r * 32 + ((kk ^ KEY(r)) * 8);
  }
#pragma unroll
  for (int n = 0; n < 6; ++n) {
    int r = wN * 96 + n * 16 + (lane & 15);
    bfoff[n] = 8192 + r * 32 + ((kk ^ KEY(r)) * 8);
  }

  f32x4 acc[4][6] = {};
  const int NT = 40;  // K = 1280

  // ---- prologue: stage tile 0 into buf 0
  {
    float4 pa0 = *(const float4*)(ag + sl0 * 8);
    float4 pa1 = *(const float4*)(ag + sl0 * 8 + 4);
    float4 pa2 = *(const float4*)(ag + sl1 * 8);
    float4 pa3 = *(const float4*)(ag + sl1 * 8 + 4);
    gload16(MtB + bsrc1, &lds[bdst1 + 8192]);
    if (tid < 256) gload16(MtB + bsrc2, &lds[bdst2 + 8192]);
    union { ushort us[8]; bf16x8 v; } c0, c1;
    c0.us[0]=f2bf(pa0.x); c0.us[1]=f2bf(pa0.y); c0.us[2]=f2bf(pa0.z); c0.us[3]=f2bf(pa0.w);
    c0.us[4]=f2bf(pa1.x); c0.us[5]=f2bf(pa1.y); c0.us[6]=f2bf(pa1.z); c0.us[7]=f2bf(pa1.w);
    c1.us[0]=f2bf(pa2.x); c1.us[1]=f2bf(pa2.y); c1.us[2]=f2bf(pa2.z); c1.us[3]=f2bf(pa2.w);
    c1.us[4]=f2bf(pa3.x); c1.us[5]=f2bf(pa3.y); c1.us[6]=f2bf(pa3.z); c1.us[7]=f2bf(pa3.w);
    *(bf16x8*)(&lds[adst0]) = c0.v;
    *(bf16x8*)(&lds[adst1]) = c1.v;
  }
  __syncthreads();

  for (int t = 0; t < NT; ++t) {
    const int cb = (t & 1) * 14336;
    const int nb = ((t & 1) ^ 1) * 14336;
    const bool pre = (t + 1 < NT);
    float4 pa0, pa1, pa2, pa3;
    if (pre) {
      const int k1 = (t + 1) * 32;
      pa0 = *(const float4*)(ag + k1 + sl0 * 8);
      pa1 = *(const float4*)(ag + k1 + sl0 * 8 + 4);
      pa2 = *(const float4*)(ag + k1 + sl1 * 8);
      pa3 = *(const float4*)(ag + k1 + sl1 * 8 + 4);
      gload16(MtB + k1 + bsrc1, &lds[nb + 8192 + bdst1]);
      if (tid < 256) gload16(MtB + k1 + bsrc2, &lds[nb + 8192 + bdst2]);
    }
    bf16x8 af[4], bfv[6];
#pragma unroll
    for (int m = 0; m < 4; ++m) af[m] = *(const bf16x8*)(&lds[cb + afoff[m]]);
#pragma unroll
    for (int n = 0; n < 6; ++n) bfv[n] = *(const bf16x8*)(&lds[cb + bfoff[n]]);
#pragma unroll
    for (int m = 0; m < 4; ++m)
#pragma unroll
      for (int n = 0; n < 6; ++n)
        acc[m][n] = __builtin_amdgcn_mfma_f32_16x16x32_bf16(af[m], bfv[n], acc[m][n], 0, 0, 0);
    if (pre) {
      union { ushort us[8]; bf16x8 v; } c0, c1;
      c0.us[0]=f2bf(pa0.x); c0.us[1]=f2bf(pa0.y); c0.us[2]=f2bf(pa0.z); c0.us[3]=f2bf(pa0.w);
      c0.us[4]=f2bf(pa1.x); c0.us[5]=f2bf(pa1.y); c0.us[6]=f2bf(pa1.z); c0.us[7]=f2bf(pa1.w);
      c1.us[0]=f2bf(pa2.x); c1.us[1]=f2bf(pa2.y); c1.us[2]=f2bf(pa2.z); c1.us[3]=f2bf(pa2.w);
      c1.us[4]=f2bf(pa3.x); c1.us[5]=f2bf(pa3.y); c1.us[6]=f2bf(pa3.z); c1.us[7]=f2bf(pa3.w);
      *(bf16x8*)(&lds[nb + adst0]) = c0.v;
      *(bf16x8*)(&lds[nb + adst1]) = c1.v;
    }
    __syncthreads();
  }

  // ---- softmax over 77 valid cols (mask col>=77), normalize in-place
  const int l15 = lane & 15;
#pragma unroll
  for (int m = 0; m < 4; ++m)
#pragma unroll
    for (int j = 0; j < 4; ++j) {
      float mx = -1e30f;
#pragma unroll
      for (int n = 0; n < 6; ++n)
        if (n * 16 + l15 < 77) mx = fmaxf(mx, acc[m][n][j]);
#pragma unroll
      for (int o = 8; o; o >>= 1) mx = fmaxf(mx, __shfl_xor(mx, o));
      float sum = 0.f;
#pragma unroll
      for (int n = 0; n < 6; ++n) {
        float e = (n * 16 + l15 < 77) ? __expf(acc[m][n][j] - mx) : 0.f;
        acc[m][n][j] = e;
        sum += e;
      }
#pragma unroll
      for (int o = 8; o; o >>= 1) sum += __shfl_xor(sum, o);
      float inv = 1.f / sum;
#pragma unroll
      for (int n = 0; n < 6; ++n) acc[m][n][j] *= inv;
    }

  // ---- LDS bounce: wave region [64][88] ushorts, then coalesced flat store
  ushort* pw = lds + wid * 5632;
#pragma unroll
  for (int m = 0; m < 4; ++m)
#pragma unroll
    for (int n = 0; n < 5; ++n)        // cols 0..79 (77..79 are zeros)
#pragma unroll
      for (int j = 0; j < 4; ++j)
        pw[(m * 16 + (lane >> 4) * 4 + j) * 88 + n * 16 + l15] = f2bf(acc[m][n][j]);

  const uint* pw32 = (const uint*)pw;
  uint* probs32 = (uint*)probs;
  const int head = h0 + wN;
  const long sbase = (long)z * 4096 + s0 + wM * 64;
#pragma unroll 4
  for (int k = 0; k < 40; ++k) {
    int f2 = k * 64 + lane;
    int r = f2 / 40;
    int tp = f2 - r * 40;
    probs32[(sbase + r) * 320 + head * 40 + tp] = pw32[r * 44 + tp];
  }
}

// ---------------- output GEMM: 256x128, BK=32, ring-4, coalesced C-write ----------------
// C[z][m][n] = sum_k P[z][m][k] * Nt[z][n][k] + bias[n].  M=4096/z, N=1280, K=640.
// FIX vs r4: A staging dest is LINEAR in lane (global_load_lds HW writes base+lane*16);
// the XOR swizzle is carried entirely on the per-lane GLOBAL source address.
__global__ __launch_bounds__(512, 2) void gemm_out(
    const ushort* __restrict__ P, const ushort* __restrict__ Nt,
    float* __restrict__ C, const float* __restrict__ bias)
{
  __shared__ ushort lds[49152];  // 4 bufs x (A 8192 | B 4096)

  const int z = blockIdx.z;
  const ushort* Ab = P + (long)z * (4096L * 640) + (long)blockIdx.x * 256 * 640;
  const ushort* Bb = Nt + (long)z * (1280L * 640) + (long)blockIdx.y * 128 * 640;
  const int tid = threadIdx.x;
  const int lane = tid & 63;
  const int wid = tid >> 6;
  const int wM = wid >> 2;   // 0..1
  const int wN = wid & 3;    // 0..3

  // staging: A 1024 chunks (2/thread: c=tid -> rows 0..127, c=tid+512 -> rows 128..255),
  // B 512 chunks (1/thread). Dests linear; sources carry the swizzle involution.
  const int ar0 = tid >> 2;              // row of chunk tid
  const int ar1 = 128 + (tid >> 2);      // row of chunk tid+512
  const int ap = tid & 3;                // phys slot
  const long aoff0 = (long)ar0 * 640 + ((ap ^ KEY(ar0)) * 8);
  const long aoff1 = (long)ar1 * 640 + ((ap ^ KEY(ar1)) * 8);
  const int adst0 = tid * 8;             // linear (byte = tid*16)
  const int adst1 = 4096 + tid * 8;      // linear
  const int brow = tid >> 2;
  const long boff = (long)brow * 640 + (((tid & 3) ^ KEY(brow)) * 8);
  const int bdst = 8192 + tid * 8;       // linear: chunk tid of B region

  const int kk = lane >> 4;
  int afoff[8], bfoff[2];
#pragma unroll
  for (int m = 0; m < 8; ++m) {
    int r = wM * 128 + m * 16 + (lane & 15);
    afoff[m] = r * 32 + ((kk ^ KEY(r)) * 8);
  }
#pragma unroll
  for (int n = 0; n < 2; ++n) {
    int r = wN * 32 + n * 16 + (lane & 15);
    bfoff[n] = 8192 + r * 32 + ((kk ^ KEY(r)) * 8);
  }

  f32x4 acc[8][2] = {};
  const int NT = 20;  // K = 640

#define SA(tt)  { int sb = ((tt) & 3) * 12288; int pk = (tt) << 5; \
    gload16(Ab + aoff0 + pk, &lds[sb + adst0]); \
    gload16(Ab + aoff1 + pk, &lds[sb + adst1]); }
#define SBl(tt) { int sb = ((tt) & 3) * 12288; int pk = (tt) << 5; \
    gload16(Bb + boff + pk, &lds[sb + bdst]); }

  SA(0) SBl(0) SA(1) SBl(1) SA(2) SBl(2)
  asm volatile("s_waitcnt vmcnt(6)" ::: "memory");   // tile 0 resident
  SBAR(); __builtin_amdgcn_s_barrier(); SBAR();

  for (int t = 0; t < NT; ++t) {
    const int base = (t & 3) * 12288;
    const bool pre = (t + 3 < NT);

    bf16x8 a0[4], a1[4], bv[2];
#pragma unroll
    for (int m = 0; m < 4; ++m) a0[m] = *(const bf16x8*)(&lds[base + afoff[m]]);
#pragma unroll
    for (int n = 0; n < 2; ++n) bv[n] = *(const bf16x8*)(&lds[base + bfoff[n]]);
    if (pre) SA(t + 3)
    SBAR(); __builtin_amdgcn_s_barrier(); SBAR();
    __builtin_amdgcn_s_setprio(1);
#pragma unroll
    for (int m = 0; m < 4; ++m)
#pragma unroll
      for (int n = 0; n < 2; ++n)
        acc[m][n] = __builtin_amdgcn_mfma_f32_16x16x32_bf16(a0[m], bv[n], acc[m][n], 0, 0, 0);
    __builtin_amdgcn_s_setprio(0);
    SBAR(); __builtin_amdgcn_s_barrier(); SBAR();

#pragma unroll
    for (int m = 0; m < 4; ++m) a1[m] = *(const bf16x8*)(&lds[base + afoff[m + 4]]);
    if (pre) SBl(t + 3)
    if (t + 3 < NT)      { asm volatile("s_waitcnt vmcnt(6)" ::: "memory"); }
    else if (t + 2 < NT) { asm volatile("s_waitcnt vmcnt(3)" ::: "memory"); }
    else                 { asm volatile("s_waitcnt vmcnt(0)" ::: "memory"); }
    SBAR(); __builtin_amdgcn_s_barrier(); SBAR();
    __builtin_amdgcn_s_setprio(1);
#pragma unroll
    for (int m = 4; m < 8; ++m)
#pragma unroll
      for (int n = 0; n < 2; ++n)
        acc[m][n] = __builtin_amdgcn_mfma_f32_16x16x32_bf16(a1[m - 4], bv[n], acc[m][n], 0, 0, 0);
    __builtin_amdgcn_s_setprio(0);
    SBAR(); __builtin_amdgcn_s_barrier(); SBAR();
  }
#undef SA
#undef SBl

  // coalesced C write via per-wave LDS bounce ([16][36] f32, pad keeps 16B align)
  float* pw = (float*)lds + wid * 576;
  const int ccol = blockIdx.y * 128 + wN * 32;
  const float4 bv4 = *(const float4*)(bias + ccol + (lane & 7) * 4);
  const long crow0 = (long)z * 4096 + blockIdx.x * 256 + wM * 128;
#pragma unroll
  for (int m = 0; m < 8; ++m) {
#pragma unroll
    for (int n = 0; n < 2; ++n)
#pragma unroll
      for (int j = 0; j < 4; ++j)
        pw[((lane >> 4) * 4 + j) * 36 + n * 16 + (lane & 15)] = acc[m][n][j];
#pragma unroll
    for (int pass = 0; pass < 2; ++pass) {
      int r = pass * 8 + (lane >> 3);
      float4 v = *(const float4*)(pw + r * 36 + (lane & 7) * 4);
      v.x += bv4.x; v.y += bv4.y; v.z += bv4.z; v.w += bv4.w;
      *(float4*)(C + (crow0 + m * 16 + r) * 1280 + ccol + (lane & 7) * 4) = v;
    }
  }
}

// Nt pad: zero cols h*80+77..79 for all b, j
__global__ void zero_nt_pad(ushort* __restrict__ Nt) {
  int idx = blockIdx.x * 256 + threadIdx.x;
  if (idx >= 8 * 1280 * 24) return;
  int b = idx / (1280 * 24);
  int rem = idx % (1280 * 24);
  int j = rem / 24, q = rem % 24;
  int h = q / 3, t = 77 + q % 3;
  Nt[(long)b * 1280 * 640 + (long)j * 640 + h * 80 + t] = 0;
}

extern "C" void kernel_launch(void* const* d_in, const int* in_sizes, int n_in,
                              void* d_out, int out_size, void* d_ws, size_t ws_size,
                              hipStream_t stream) {
  (void)in_sizes; (void)n_in; (void)out_size; (void)ws_size;
  const float* hs     = (const float*)d_in[0];
  const float* ehs    = (const float*)d_in[1];
  const float* Wq     = (const float*)d_in[2];
  const float* Wk     = (const float*)d_in[3];
  const float* Wv     = (const float*)d_in[4];
  const float* Wo     = (const float*)d_in[5];
  const float* bo     = (const float*)d_in[6];
  const float* q_down = (const float*)d_in[7];
  const float* q_up   = (const float*)d_in[8];
  const float* k_down = (const float*)d_in[9];
  const float* k_up   = (const float*)d_in[10];
  const float* v_down = (const float*)d_in[11];
  const float* v_up   = (const float*)d_in[12];
  const float* o_down = (const float*)d_in[13];
  const float* o_up   = (const float*)d_in[14];

  char* w = (char*)d_ws;
  size_t off = 0;
  auto alloc = [&](size_t b) { char* p = w + off; off = (off + b + 255) & ~(size_t)255; return p; };
  ushort* ehs_bf = (ushort*)alloc(616L * 768 * 2);
  ushort* WqT    = (ushort*)alloc(1280L * 1280 * 2);   // Wq_eff^T * inv_sqrt(DH)
  ushort* Wkv    = (ushort*)alloc(2560L * 768 * 2);    // [Wk_eff; Wv_eff]
  ushort* Wo_bf  = (ushort*)alloc(1280L * 1280 * 2);
  ushort* kv_bf  = (ushort*)alloc(616L * 2560 * 2);    // k | v
  ushort* Mt     = (ushort*)alloc(8L * 640 * 1280 * 2);
  ushort* Nt     = (ushort*)alloc(8L * 1280 * 640 * 2);  // col = h*80+t
  ushort* probs  = (ushort*)alloc(8L * 4096 * 640 * 2);  // col = h*80+t
  float*  outp   = (float*)d_out;
  const float invs = 0.07905694150420949f;  // 1/sqrt(160)

  // fold LoRA into effective weights (bf16)
  fold_kernel<<<6400, 256, 0, stream>>>(Wq, q_up, q_down, WqT, 1280, 1280, 1, invs);
  fold_kernel<<<3840, 256, 0, stream>>>(Wk, k_up, k_down, Wkv, 1280, 768, 0, 1.0f);
  fold_kernel<<<3840, 256, 0, stream>>>(Wv, v_up, v_down, Wkv + 1280L * 768, 1280, 768, 0, 1.0f);
  fold_kernel<<<6400, 256, 0, stream>>>(Wo, o_up, o_down, Wo_bf, 1280, 1280, 0, 1.0f);
  cvt_kernel<<<231, 256, 0, stream>>>(ehs, ehs_bf, 59136);
  // fused k|v projection: (616x768)@(768->2560), bf16 out
  gemm_bt<<<dim3(5, 20, 1), 256, 0, stream>>>(ehs_bf, 0, 0, 768, 616,
      Wkv, 0, 0, 768, 2560, nullptr, kv_bf, 0, 0, 2560, nullptr, 768);
  // Mt[b][h*77+t][i] = inv_sqrt * sum_d k[b,t,h*160+d] * Wq_eff[h*160+d][i]   (z = b*8+h)
  gemm_bt<<<dim3(1, 10, 64), 256, 0, stream>>>(kv_bf, 77L * 2560, 160, 2560, 77,
      WqT, 0, 160, 1280, 1280, nullptr, Mt, 640L * 1280, 77L * 1280, 1280, nullptr, 160);
  // Nt[b][j][h*80+t] = sum_d Wo_eff[j][h*160+d] * v[b,t,h*160+d]
  gemm_bt<<<dim3(10, 1, 64), 256, 0, stream>>>(Wo_bf, 0, 160, 1280, 1280,
      kv_bf + 1280, 77L * 2560, 160, 2560, 77, nullptr, Nt, 1280L * 640, 80, 640, nullptr, 160);
  zero_nt_pad<<<960, 256, 0, stream>>>(Nt);
  // fused scores + softmax -> probs bf16
  score_softmax<<<dim3(16, 4, 8), 512, 0, stream>>>(hs, Mt, probs);
  // out = probs @ Nt^T + bo
  gemm_out<<<dim3(16, 10, 8), 512, 0, stream>>>(probs, Nt, outp, bo);
}